// Round 17
// baseline (318.539 us; speedup 1.0000x reference)
//
#include <hip/hip_runtime.h>

// GCN on 1M nodes / 16M edges, collapsed to scalar per-node features.
//
//   deg[c]  = sum_{e: col=c} ew[e] + 1 (self loop)
//   dis     = rsqrt(deg)
//   S1[c]   = dis[c] * (sum_e dis[row]*ew*x[row]) + dis[c]^2 * x[c]
//   g[c]    = sum_j relu(S1[c]*W1[j] + b1[j]) * W2[j]
//   S2[c]   = dis[c] * (sum_e dis[row]*ew*g[row]) + dis[c]^2 * g[c]
//   y[c]    = sigmoid((S2[c]+b2)*Wl + bl)
//
// R16 post-mortem: fill pinned at ~100us across occupancy 34->68% -> bound
// by per-edge LDS ops (2 atomics + 3 stage writes + 3 reads), not waves.
// R17: slot-passing. k_count's histogram atomicAdd RETURN VALUE is the
// within-(block,bucket) slot; store it (slot16, coalesced u16). k_fill then
// needs ZERO LDS atomics: reload count row (k_t2 now writes offsets to a
// separate histT2, preserving counts), register wave-scan -> lb, stage at
// lb[bk]+slot. Barriers 5 -> 3. Costs +64MB HBM (slot write+read).

constexpr int N_NODES = 1000000;
constexpr int N_EDGES = 16000000;

constexpr int BSHIFT = 12;
constexpr int BNODES = 1 << BSHIFT;                    // 4096 nodes/bucket
constexpr int NB = (N_NODES + BNODES - 1) / BNODES;    // 245 buckets
constexpr int FBLK_C = 512;                            // count threads
constexpr int EPT_C = 12;
constexpr int FBLK_F = 1024;                           // fill threads
constexpr int EPT_F = 6;
constexpr int CHUNK = FBLK_C * EPT_C;                  // 6144 (== FBLK_F*EPT_F)
constexpr int NBLK = (N_EDGES + CHUNK - 1) / CHUNK;    // 2605
constexpr int NHIST = NB * NBLK;                       // 638,225
constexpr int SCAN_TPB = 256;
constexpr int SCAN_EPB = 1024;
constexpr int NSCAN = (NHIST + SCAN_EPB - 1) / SCAN_EPB;  // 624
constexpr int NHIST_PAD = NSCAN * SCAN_EPB;            // 638,976

__device__ inline unsigned short f2bf(float f) {   // fp32 -> bf16 RNE
  unsigned u = __float_as_uint(f);
  return (unsigned short)((u + 0x7FFFu + ((u >> 16) & 1u)) >> 16);
}
__device__ inline float bf2f(unsigned short h) {
  return __uint_as_float((unsigned)h << 16);
}
// packed-pair bf16 unpack: lo = u<<16 (1 op), hi = u & 0xFFFF0000 (1 op)
__device__ inline float blo(unsigned u) { return __uint_as_float(u << 16); }
__device__ inline float bhi(unsigned u) { return __uint_as_float(u & 0xFFFF0000u); }

// ---------------- build: count(+slots) / transpose / scan / fill ------------

// histT layout [NBLK][256] (counts, PRESERVED); slot16[e] = arrival index of
// edge e within its (block,bucket) group — the atomicAdd return value.
__global__ __launch_bounds__(FBLK_C) void k_count(const int* __restrict__ col,
                                                  unsigned* __restrict__ histT,
                                                  unsigned short* __restrict__ slot16) {
  __shared__ unsigned cnt[256];
  int t = threadIdx.x;
  if (t < 256) cnt[t] = 0;
  __syncthreads();
  int e0 = blockIdx.x * CHUNK;
  if (e0 + CHUNK <= N_EDGES) {          // fast path: all loads unguarded
    int c[EPT_C];
#pragma unroll
    for (int k = 0; k < EPT_C; ++k) c[k] = col[e0 + k * FBLK_C + t];
    __builtin_amdgcn_sched_barrier(0);  // keep the load batch issued together
#pragma unroll
    for (int k = 0; k < EPT_C; ++k) {
      unsigned old = atomicAdd(&cnt[c[k] >> BSHIFT], 1u);
      slot16[e0 + k * FBLK_C + t] = (unsigned short)old;   // coalesced per k
    }
  } else {
#pragma unroll
    for (int k = 0; k < EPT_C; ++k) {
      int e = e0 + k * FBLK_C + t;
      if (e < N_EDGES) {
        unsigned old = atomicAdd(&cnt[col[e] >> BSHIFT], 1u);
        slot16[e] = (unsigned short)old;
      }
    }
  }
  __syncthreads();
  if (t < 256) histT[(size_t)blockIdx.x * 256 + t] = cnt[t];
}

// histT[NBLK][256] -> hist[b*NBLK + blk] (bucket-major flat, for linear scan)
__global__ __launch_bounds__(1024) void k_t1(const unsigned* __restrict__ in,
                                             unsigned* __restrict__ out) {
  __shared__ unsigned tile[32][33];
  int bx = blockIdx.x * 32;   // blk base
  int by = blockIdx.y * 32;   // b base
  int tx = threadIdx.x, ty = threadIdx.y;
  int rblk = bx + ty;
  if (rblk < NBLK) tile[ty][tx] = in[(size_t)rblk * 256 + by + tx];
  __syncthreads();
  int wb = by + ty, wblk = bx + tx;
  if (wb < NB && wblk < NBLK) out[(size_t)wb * NBLK + wblk] = tile[tx][ty];
}

// hist offsets (bucket-major) -> histT2[blk*256 + b] (fill reads coalesced).
// Writes a SEPARATE buffer so histT (counts) survives for k_fill's scan.
__global__ __launch_bounds__(1024) void k_t2(const unsigned* __restrict__ in,
                                             unsigned* __restrict__ out) {
  __shared__ unsigned tile[32][33];
  int bx = blockIdx.x * 32;   // blk base
  int by = blockIdx.y * 32;   // b base
  int tx = threadIdx.x, ty = threadIdx.y;
  int rb = by + ty, rblk = bx + tx;
  if (rb < NB && rblk < NBLK) tile[ty][tx] = in[(size_t)rb * NBLK + rblk];
  __syncthreads();
  int wblk = bx + ty, wb = by + tx;
  if (wblk < NBLK && wb < NB) out[(size_t)wblk * 256 + wb] = tile[tx][ty];
}

__global__ __launch_bounds__(SCAN_TPB) void k_scanA(unsigned* __restrict__ h,
                                                    unsigned* __restrict__ bsum) {
  __shared__ unsigned sc[SCAN_TPB];
  int t = threadIdx.x;
  size_t base = (size_t)blockIdx.x * SCAN_EPB + (size_t)t * 4;
  uint4 v = *(const uint4*)(h + base);
  unsigned s = v.x + v.y + v.z + v.w;
  sc[t] = s;
  __syncthreads();
  for (int d = 1; d < SCAN_TPB; d <<= 1) {
    unsigned u = (t >= d) ? sc[t - d] : 0;
    __syncthreads();
    sc[t] += u;
    __syncthreads();
  }
  unsigned ex = sc[t] - s;
  uint4 o;
  o.x = ex; o.y = ex + v.x; o.z = ex + v.x + v.y; o.w = ex + v.x + v.y + v.z;
  *(uint4*)(h + base) = o;
  if (t == SCAN_TPB - 1) bsum[blockIdx.x] = sc[t];
}

__global__ __launch_bounds__(1024) void k_scanB(unsigned* __restrict__ bsum) {
  __shared__ unsigned sc[1024];
  int t = threadIdx.x;
  unsigned a0 = (2 * t < NSCAN) ? bsum[2 * t] : 0;
  unsigned a1 = (2 * t + 1 < NSCAN) ? bsum[2 * t + 1] : 0;
  unsigned s = a0 + a1;
  sc[t] = s;
  __syncthreads();
  for (int d = 1; d < 1024; d <<= 1) {
    unsigned u = (t >= d) ? sc[t - d] : 0;
    __syncthreads();
    sc[t] += u;
    __syncthreads();
  }
  unsigned ex = sc[t] - s;
  if (2 * t < NSCAN) bsum[2 * t] = ex;
  if (2 * t + 1 < NSCAN) bsum[2 * t + 1] = ex + a0;
}

__global__ __launch_bounds__(SCAN_TPB) void k_scanC(unsigned* __restrict__ h,
                                                    const unsigned* __restrict__ bsum) {
  unsigned add = bsum[blockIdx.x];
  size_t base = (size_t)blockIdx.x * SCAN_EPB + (size_t)threadIdx.x * 4;
  uint4 v = *(uint4*)(h + base);
  v.x += add; v.y += add; v.z += add; v.w += add;
  *(uint4*)(h + base) = v;
}

// Slot-directed LDS-reorder fill, SoA output: PK (u32) + W16 (bf16).
// ZERO LDS atomics: stage position = lb[bucket] + slot16[e]; lb from a
// register wave-scan of the preserved count row. 3 barriers total.
__global__ __launch_bounds__(FBLK_F) void k_fill(const int* __restrict__ row,
                                                 const int* __restrict__ col,
                                                 const float* __restrict__ ew,
                                                 const unsigned short* __restrict__ slot16,
                                                 const unsigned* __restrict__ histT,
                                                 const unsigned* __restrict__ histT2,
                                                 unsigned* __restrict__ PK,
                                                 unsigned short* __restrict__ W16) {
  __shared__ unsigned lb[256];
  __shared__ unsigned gbase[256];
  __shared__ unsigned wsum[4];
  __shared__ unsigned spk[CHUNK];          // 24KB
  __shared__ unsigned short sw[CHUNK];     // 12KB
  __shared__ unsigned char sbkt[CHUNK];    // 6KB

  int t = threadIdx.x;
  int blk = blockIdx.x;
  unsigned own = 0, v = 0;
  if (t < 256) {
    gbase[t] = histT2[(size_t)blk * 256 + t];   // global offsets (coalesced)
    own = histT[(size_t)blk * 256 + t];         // counts (coalesced)
    v = own;
#pragma unroll
    for (int d = 1; d < 64; d <<= 1) {
      unsigned u = __shfl_up(v, d, 64);
      if ((t & 63) >= d) v += u;
    }
    if ((t & 63) == 63) wsum[t >> 6] = v;
  }
  __syncthreads();                              // B1: wsum ready
  unsigned total = wsum[0] + wsum[1] + wsum[2] + wsum[3];
  if (t < 256) {
    unsigned wbase = 0;
#pragma unroll
    for (int w = 0; w < 4; ++w)
      if (w < (t >> 6)) wbase += wsum[w];
    lb[t] = wbase + v - own;                    // exclusive local prefix
  }
  __syncthreads();                              // B2: lb ready

  int e0 = blk * CHUNK;
  if (e0 + CHUNK <= N_EDGES) {                  // fast path (2604 of 2605)
    int cv[EPT_F], rv[EPT_F];
    float wf[EPT_F];
    unsigned short sl[EPT_F];
#pragma unroll
    for (int k = 0; k < EPT_F; ++k) {
      int e = e0 + k * FBLK_F + t;
      cv[k] = col[e];
      rv[k] = row[e];
      wf[k] = ew[e];
      sl[k] = slot16[e];
    }
    __builtin_amdgcn_sched_barrier(0);          // 24 loads in flight first
#pragma unroll
    for (int k = 0; k < EPT_F; ++k) {
      int bk = cv[k] >> BSHIFT;
      unsigned pos = lb[bk] + sl[k];
      spk[pos] = ((unsigned)rv[k] << BSHIFT) | (unsigned)(cv[k] & (BNODES - 1));
      sw[pos] = f2bf(wf[k]);
      sbkt[pos] = (unsigned char)bk;
    }
  } else {
#pragma unroll
    for (int k = 0; k < EPT_F; ++k) {
      int e = e0 + k * FBLK_F + t;
      if (e < N_EDGES) {
        int c = col[e];
        int bk = c >> BSHIFT;
        unsigned pos = lb[bk] + slot16[e];
        spk[pos] = ((unsigned)row[e] << BSHIFT) | (unsigned)(c & (BNODES - 1));
        sw[pos] = f2bf(ew[e]);
        sbkt[pos] = (unsigned char)bk;
      }
    }
  }
  __syncthreads();                              // B3: stage complete

  // staged order is bucket-sorted: consecutive s -> consecutive global dest.
  unsigned s = t;
  for (; s + 3u * FBLK_F < total; s += 4u * FBLK_F) {
#pragma unroll
    for (int u = 0; u < 4; ++u) {
      unsigned si = s + u * FBLK_F;
      unsigned b = sbkt[si];
      unsigned idx = gbase[b] + (si - lb[b]);
      PK[idx] = spk[si];
      W16[idx] = sw[si];
    }
  }
  for (; s < total; s += FBLK_F) {
    unsigned b = sbkt[s];
    unsigned idx = gbase[b] + (s - lb[b]);
    PK[idx] = spk[s];
    W16[idx] = sw[s];
  }
}

// ---------------- accumulate: one (bucket,part) per block ----------------
// mode 0: val = ew. mode 1: val = ew * bf16 p16[row].
// FIXED-POINT LDS accumulator (ds_add_u32 ~5x faster than ds_add_f32).
constexpr int ABLK = 512;

__global__ __launch_bounds__(ABLK) void k_acc(const unsigned* __restrict__ PK,
                                              const unsigned short* __restrict__ W16,
                                              const unsigned* __restrict__ hist,
                                              const unsigned short* __restrict__ p16,
                                              float* __restrict__ out,
                                              int mode, int split,
                                              float FS, float INV) {
  __shared__ int acc[BNODES];
  {
    int4* a4 = (int4*)acc;
#pragma unroll
    for (int i = threadIdx.x; i < BNODES / 4; i += ABLK)
      a4[i] = make_int4(0, 0, 0, 0);
  }
  __syncthreads();
  int b = blockIdx.x / split;
  int part = blockIdx.x - b * split;
  unsigned bs = hist[(size_t)b * NBLK];
  unsigned be = (b + 1 < NB) ? hist[(size_t)(b + 1) * NBLK] : (unsigned)N_EDGES;
  unsigned len = be - bs;
  unsigned s = bs + (unsigned)(((unsigned long long)len * part) / split);
  unsigned e = bs + (unsigned)(((unsigned long long)len * (part + 1)) / split);
  unsigned t = threadIdx.x;

  unsigned s_al = (s + 7u) & ~7u;        // align to 8 records
  if (s_al > e) s_al = e;
  if (t == 0) {                          // scalar head (<8 records)
    for (unsigned i = s; i < s_al; ++i) {
      unsigned pk = PK[i];
      float v = bf2f(W16[i]);
      if (mode) v *= bf2f(p16[pk >> BSHIFT]);
      atomicAdd(&acc[pk & (BNODES - 1)], __float2int_rn(v * FS));
    }
  }
  s = s_al;
  unsigned n = (e > s) ? (e - s) : 0u;
  unsigned ng = n >> 3;                  // groups of 8 records
  const uint4* pk4 = (const uint4*)(PK + s);    // group g: pk4[2g], pk4[2g+1]
  const uint4* w4  = (const uint4*)(W16 + s);   // group g: w4[g] (8 bf16)

  unsigned ip = t;
  for (; ip + ABLK < ng; ip += 2u * ABLK) {     // 2 groups = 16 records
    unsigned g1 = ip + ABLK;
    uint4 pA0 = pk4[2u * ip], pA1 = pk4[2u * ip + 1u];
    uint4 pB0 = pk4[2u * g1], pB1 = pk4[2u * g1 + 1u];
    uint4 wA = w4[ip], wB = w4[g1];
    __builtin_amdgcn_sched_barrier(0);   // 6 loads issued before any use
    if (mode) {
      unsigned short gA0 = p16[pA0.x >> BSHIFT], gA1 = p16[pA0.y >> BSHIFT];
      unsigned short gA2 = p16[pA0.z >> BSHIFT], gA3 = p16[pA0.w >> BSHIFT];
      unsigned short gA4 = p16[pA1.x >> BSHIFT], gA5 = p16[pA1.y >> BSHIFT];
      unsigned short gA6 = p16[pA1.z >> BSHIFT], gA7 = p16[pA1.w >> BSHIFT];
      unsigned short gB0 = p16[pB0.x >> BSHIFT], gB1 = p16[pB0.y >> BSHIFT];
      unsigned short gB2 = p16[pB0.z >> BSHIFT], gB3 = p16[pB0.w >> BSHIFT];
      unsigned short gB4 = p16[pB1.x >> BSHIFT], gB5 = p16[pB1.y >> BSHIFT];
      unsigned short gB6 = p16[pB1.z >> BSHIFT], gB7 = p16[pB1.w >> BSHIFT];
      __builtin_amdgcn_sched_barrier(0); // 16 gathers in flight before use
      atomicAdd(&acc[pA0.x & (BNODES - 1)], __float2int_rn(blo(wA.x) * bf2f(gA0) * FS));
      atomicAdd(&acc[pA0.y & (BNODES - 1)], __float2int_rn(bhi(wA.x) * bf2f(gA1) * FS));
      atomicAdd(&acc[pA0.z & (BNODES - 1)], __float2int_rn(blo(wA.y) * bf2f(gA2) * FS));
      atomicAdd(&acc[pA0.w & (BNODES - 1)], __float2int_rn(bhi(wA.y) * bf2f(gA3) * FS));
      atomicAdd(&acc[pA1.x & (BNODES - 1)], __float2int_rn(blo(wA.z) * bf2f(gA4) * FS));
      atomicAdd(&acc[pA1.y & (BNODES - 1)], __float2int_rn(bhi(wA.z) * bf2f(gA5) * FS));
      atomicAdd(&acc[pA1.z & (BNODES - 1)], __float2int_rn(blo(wA.w) * bf2f(gA6) * FS));
      atomicAdd(&acc[pA1.w & (BNODES - 1)], __float2int_rn(bhi(wA.w) * bf2f(gA7) * FS));
      atomicAdd(&acc[pB0.x & (BNODES - 1)], __float2int_rn(blo(wB.x) * bf2f(gB0) * FS));
      atomicAdd(&acc[pB0.y & (BNODES - 1)], __float2int_rn(bhi(wB.x) * bf2f(gB1) * FS));
      atomicAdd(&acc[pB0.z & (BNODES - 1)], __float2int_rn(blo(wB.y) * bf2f(gB2) * FS));
      atomicAdd(&acc[pB0.w & (BNODES - 1)], __float2int_rn(bhi(wB.y) * bf2f(gB3) * FS));
      atomicAdd(&acc[pB1.x & (BNODES - 1)], __float2int_rn(blo(wB.z) * bf2f(gB4) * FS));
      atomicAdd(&acc[pB1.y & (BNODES - 1)], __float2int_rn(bhi(wB.z) * bf2f(gB5) * FS));
      atomicAdd(&acc[pB1.z & (BNODES - 1)], __float2int_rn(blo(wB.w) * bf2f(gB6) * FS));
      atomicAdd(&acc[pB1.w & (BNODES - 1)], __float2int_rn(bhi(wB.w) * bf2f(gB7) * FS));
    } else {
      atomicAdd(&acc[pA0.x & (BNODES - 1)], __float2int_rn(blo(wA.x) * FS));
      atomicAdd(&acc[pA0.y & (BNODES - 1)], __float2int_rn(bhi(wA.x) * FS));
      atomicAdd(&acc[pA0.z & (BNODES - 1)], __float2int_rn(blo(wA.y) * FS));
      atomicAdd(&acc[pA0.w & (BNODES - 1)], __float2int_rn(bhi(wA.y) * FS));
      atomicAdd(&acc[pA1.x & (BNODES - 1)], __float2int_rn(blo(wA.z) * FS));
      atomicAdd(&acc[pA1.y & (BNODES - 1)], __float2int_rn(bhi(wA.z) * FS));
      atomicAdd(&acc[pA1.z & (BNODES - 1)], __float2int_rn(blo(wA.w) * FS));
      atomicAdd(&acc[pA1.w & (BNODES - 1)], __float2int_rn(bhi(wA.w) * FS));
      atomicAdd(&acc[pB0.x & (BNODES - 1)], __float2int_rn(blo(wB.x) * FS));
      atomicAdd(&acc[pB0.y & (BNODES - 1)], __float2int_rn(bhi(wB.x) * FS));
      atomicAdd(&acc[pB0.z & (BNODES - 1)], __float2int_rn(blo(wB.y) * FS));
      atomicAdd(&acc[pB0.w & (BNODES - 1)], __float2int_rn(bhi(wB.y) * FS));
      atomicAdd(&acc[pB1.x & (BNODES - 1)], __float2int_rn(blo(wB.z) * FS));
      atomicAdd(&acc[pB1.y & (BNODES - 1)], __float2int_rn(bhi(wB.z) * FS));
      atomicAdd(&acc[pB1.z & (BNODES - 1)], __float2int_rn(blo(wB.w) * FS));
      atomicAdd(&acc[pB1.w & (BNODES - 1)], __float2int_rn(bhi(wB.w) * FS));
    }
  }
  for (; ip < ng; ip += 2u * ABLK) {     // leftover single group (8 records)
    uint4 p0 = pk4[2u * ip], p1 = pk4[2u * ip + 1u];
    uint4 w = w4[ip];
    float v0 = blo(w.x), v1 = bhi(w.x), v2 = blo(w.y), v3 = bhi(w.y);
    float v4 = blo(w.z), v5 = bhi(w.z), v6 = blo(w.w), v7 = bhi(w.w);
    if (mode) {
      v0 *= bf2f(p16[p0.x >> BSHIFT]); v1 *= bf2f(p16[p0.y >> BSHIFT]);
      v2 *= bf2f(p16[p0.z >> BSHIFT]); v3 *= bf2f(p16[p0.w >> BSHIFT]);
      v4 *= bf2f(p16[p1.x >> BSHIFT]); v5 *= bf2f(p16[p1.y >> BSHIFT]);
      v6 *= bf2f(p16[p1.z >> BSHIFT]); v7 *= bf2f(p16[p1.w >> BSHIFT]);
    }
    atomicAdd(&acc[p0.x & (BNODES - 1)], __float2int_rn(v0 * FS));
    atomicAdd(&acc[p0.y & (BNODES - 1)], __float2int_rn(v1 * FS));
    atomicAdd(&acc[p0.z & (BNODES - 1)], __float2int_rn(v2 * FS));
    atomicAdd(&acc[p0.w & (BNODES - 1)], __float2int_rn(v3 * FS));
    atomicAdd(&acc[p1.x & (BNODES - 1)], __float2int_rn(v4 * FS));
    atomicAdd(&acc[p1.y & (BNODES - 1)], __float2int_rn(v5 * FS));
    atomicAdd(&acc[p1.z & (BNODES - 1)], __float2int_rn(v6 * FS));
    atomicAdd(&acc[p1.w & (BNODES - 1)], __float2int_rn(v7 * FS));
  }
  unsigned rem = n & 7u;                 // scalar tail, threads 0..rem-1
  if (t < rem) {
    unsigned i = s + (n - rem) + t;
    unsigned pk = PK[i];
    float v = bf2f(W16[i]);
    if (mode) v *= bf2f(p16[pk >> BSHIFT]);
    atomicAdd(&acc[pk & (BNODES - 1)], __float2int_rn(v * FS));
  }
  __syncthreads();

  float* o = out + (size_t)part * N_NODES;
  int base = b * BNODES;
  if (base + BNODES <= N_NODES) {        // full bucket: float4 writeout
    float4* o4 = (float4*)(o + base);
    const int4* a4 = (const int4*)acc;
#pragma unroll
    for (int j = threadIdx.x; j < BNODES / 4; j += ABLK) {
      int4 q = a4[j];
      o4[j] = make_float4((float)q.x * INV, (float)q.y * INV,
                          (float)q.z * INV, (float)q.w * INV);
    }
  } else {
    for (int j = threadIdx.x; base + j < N_NODES; j += ABLK)
      o[base + j] = (float)acc[j] * INV;
  }
}

// ---------------- node-wise kernels ----------------

__global__ void k_dis_p(const float* __restrict__ x, const float* __restrict__ D,
                        float* __restrict__ A, unsigned short* __restrict__ P16,
                        int split) {
  int i = blockIdx.x * blockDim.x + threadIdx.x;
  if (i >= N_NODES) return;
  float deg = 1.0f;                       // self loop
  for (int j = 0; j < split; ++j) deg += D[(size_t)j * N_NODES + i];
  float d = rsqrtf(deg);
  A[i] = d;
  P16[i] = f2bf(d * x[i]);
}

__global__ void k_g2(const float* __restrict__ A, const float* __restrict__ x,
                     const float* __restrict__ D, unsigned short* __restrict__ P16,
                     const float* __restrict__ W1, const float* __restrict__ b1,
                     const float* __restrict__ W2, int split) {
  int i = blockIdx.x * blockDim.x + threadIdx.x;
  if (i >= N_NODES) return;
  float d = A[i];
  float sraw = 0.f;
  for (int j = 0; j < split; ++j) sraw += D[(size_t)j * N_NODES + i];
  float s1 = d * sraw + d * d * x[i];
  float g = 0.f;
#pragma unroll
  for (int j = 0; j < 4; ++j) {
    float h = fmaf(s1, W1[j], b1[j]);
    g = fmaf(fmaxf(h, 0.f), W2[j], g);
  }
  P16[i] = f2bf(d * g);
}

__global__ void k_out2(const float* __restrict__ A,
                       const unsigned short* __restrict__ P16,
                       const float* __restrict__ D, const float* __restrict__ b2,
                       const float* __restrict__ Wl, const float* __restrict__ bl,
                       float* __restrict__ y, int split) {
  int i = blockIdx.x * blockDim.x + threadIdx.x;
  if (i >= N_NODES) return;
  float d = A[i];
  float g = bf2f(P16[i]) / d;             // d in (0,1], safe
  float sraw = 0.f;
  for (int j = 0; j < split; ++j) sraw += D[(size_t)j * N_NODES + i];
  float agg2 = d * sraw + d * d * g;
  float v = fmaf(agg2 + b2[0], Wl[0], bl[0]);
  y[i] = 1.0f / (1.0f + expf(-v));
}

// ---------------- fallback (round-2 global-atomic path) ----------------

__global__ void f_deg(const int* __restrict__ col, const float* __restrict__ ew,
                      float* __restrict__ deg) {
  int i = blockIdx.x * blockDim.x + threadIdx.x;
  int stride = gridDim.x * blockDim.x;
  for (int e = i; e < N_EDGES; e += stride) atomicAdd(&deg[col[e]], ew[e]);
}
__global__ void f_dis(float* __restrict__ a) {
  int i = blockIdx.x * blockDim.x + threadIdx.x;
  if (i < N_NODES) a[i] = rsqrtf(a[i] + 1.0f);
}
__global__ void f_scatter(const int* __restrict__ row, const int* __restrict__ col,
                          const float* __restrict__ ew, const float* __restrict__ dis,
                          const float* __restrict__ src, float* __restrict__ acc) {
  int i = blockIdx.x * blockDim.x + threadIdx.x;
  int stride = gridDim.x * blockDim.x;
  for (int e = i; e < N_EDGES; e += stride) {
    int r = row[e]; int c = col[e];
    atomicAdd(&acc[c], dis[r] * ew[e] * src[r]);
  }
}
__global__ void f_g(const float* __restrict__ dis, const float* __restrict__ x,
                    float* __restrict__ s1g, const float* __restrict__ W1,
                    const float* __restrict__ b1, const float* __restrict__ W2) {
  int i = blockIdx.x * blockDim.x + threadIdx.x;
  if (i >= N_NODES) return;
  float d = dis[i];
  float s1 = d * s1g[i] + d * d * x[i];
  float g = 0.f;
#pragma unroll
  for (int j = 0; j < 4; ++j) {
    float h = fmaf(s1, W1[j], b1[j]);
    g = fmaf(fmaxf(h, 0.f), W2[j], g);
  }
  s1g[i] = g;
}
__global__ void f_out(const float* __restrict__ dis, const float* __restrict__ g,
                      float* __restrict__ s2out, const float* __restrict__ b2,
                      const float* __restrict__ Wl, const float* __restrict__ bl) {
  int i = blockIdx.x * blockDim.x + threadIdx.x;
  if (i >= N_NODES) return;
  float d = dis[i];
  float agg2 = d * s2out[i] + d * d * g[i];
  float v = fmaf(agg2 + b2[0], Wl[0], bl[0]);
  s2out[i] = 1.0f / (1.0f + expf(-v));
}

// ---------------- launch ----------------

extern "C" void kernel_launch(void* const* d_in, const int* in_sizes, int n_in,
                              void* d_out, int out_size, void* d_ws, size_t ws_size,
                              hipStream_t stream) {
  const float* x  = (const float*)d_in[0];
  const int* ei   = (const int*)d_in[1];   // int32 (harness narrows int64)
  const float* ew = (const float*)d_in[2];
  const float* W1 = (const float*)d_in[3];
  const float* b1 = (const float*)d_in[4];
  const float* W2 = (const float*)d_in[5];
  const float* b2 = (const float*)d_in[6];
  const float* Wl = (const float*)d_in[7];
  const float* bl = (const float*)d_in[8];

  const int* row = ei;
  const int* col = ei + N_EDGES;

  auto pad = [](size_t v) { return (v + 255) & ~(size_t)255; };
  const size_t PK_B     = pad((size_t)N_EDGES * 4);        // 64,000,000
  const size_t W16_B    = pad((size_t)N_EDGES * 2);        // 32,000,000
  const size_t SLOT_B   = pad((size_t)N_EDGES * 2);        // 32,000,000
  const size_t HIST_B   = pad((size_t)NHIST_PAD * 4);      // 2,555,904
  const size_t HISTT_B  = pad((size_t)NBLK * 256 * 4);     // counts
  const size_t HISTT2_B = pad((size_t)NBLK * 256 * 4);     // offsets
  const size_t BSUM_B   = 8192;
  const size_t NODE_B   = pad((size_t)N_NODES * 4);
  const size_t P16_B    = pad((size_t)N_NODES * 2);
  const size_t BASE     = PK_B + W16_B + SLOT_B + HIST_B + HISTT_B + HISTT2_B +
                          BSUM_B + NODE_B + P16_B;

  dim3 blk(256);
  dim3 ngrid((N_NODES + 255) / 256);
  dim3 tgrid((NBLK + 31) / 32, 8);
  dim3 tblk(32, 32);

  // fixed-point scales: deg <= 64 -> 2^22 (max 2^28); s1/s2 worst |sum| ~2e5
  // -> 2^12 (range +-2^19 after sum; resolution 2.4e-4 << absmax margin)
  const float FS0 = 4194304.f, INV0 = 1.f / 4194304.f;
  const float FS1 = 4096.f,    INV1 = 1.f / 4096.f;

  int split = 0;
  for (int s : {4, 2, 1})
    if (ws_size >= BASE + (size_t)s * NODE_B) { split = s; break; }

  if (split) {
    char* w = (char*)d_ws;
    unsigned* PK          = (unsigned*)w;
    unsigned short* W16   = (unsigned short*)(w + PK_B);
    unsigned short* SLOT  = (unsigned short*)(w + PK_B + W16_B);
    unsigned* hist        = (unsigned*)(w + PK_B + W16_B + SLOT_B);
    unsigned* histT       = (unsigned*)(w + PK_B + W16_B + SLOT_B + HIST_B);
    unsigned* histT2      = (unsigned*)(w + PK_B + W16_B + SLOT_B + HIST_B + HISTT_B);
    unsigned* bsum        = (unsigned*)(w + PK_B + W16_B + SLOT_B + HIST_B +
                                        HISTT_B + HISTT2_B);
    float* A              = (float*)((char*)bsum + BSUM_B);
    unsigned short* P16   = (unsigned short*)((char*)A + NODE_B);
    float* D              = (float*)((char*)P16 + P16_B);  // split partials

    // zero the scan pad tail (rest of hist fully written by k_t1)
    hipMemsetAsync(hist + NHIST, 0, (size_t)(NHIST_PAD - NHIST) * 4, stream);

    k_count<<<NBLK, FBLK_C, 0, stream>>>(col, histT, SLOT);
    k_t1   <<<tgrid, tblk, 0, stream>>>(histT, hist);
    k_scanA<<<NSCAN, SCAN_TPB, 0, stream>>>(hist, bsum);
    k_scanB<<<1, 1024, 0, stream>>>(bsum);
    k_scanC<<<NSCAN, SCAN_TPB, 0, stream>>>(hist, bsum);
    k_t2   <<<tgrid, tblk, 0, stream>>>(hist, histT2);     // offsets (separate)
    k_fill <<<NBLK, FBLK_F, 0, stream>>>(row, col, ew, SLOT, histT, histT2, PK, W16);

    k_acc  <<<NB * split, ABLK, 0, stream>>>(PK, W16, hist, nullptr, D, 0, split, FS0, INV0);
    k_dis_p<<<ngrid, blk, 0, stream>>>(x, D, A, P16, split);
    k_acc  <<<NB * split, ABLK, 0, stream>>>(PK, W16, hist, P16, D, 1, split, FS1, INV1);
    k_g2   <<<ngrid, blk, 0, stream>>>(A, x, D, P16, W1, b1, W2, split);
    k_acc  <<<NB * split, ABLK, 0, stream>>>(PK, W16, hist, P16, D, 1, split, FS1, INV1);
    k_out2 <<<ngrid, blk, 0, stream>>>(A, P16, D, b2, Wl, bl, (float*)d_out, split);
  } else {
    float* Aw = (float*)d_ws;
    float* Bw = Aw + N_NODES;
    float* Cw = (float*)d_out;
    hipMemsetAsync(d_ws, 0, 2ull * N_NODES * 4, stream);
    hipMemsetAsync(d_out, 0, (size_t)N_NODES * 4, stream);
    dim3 egrid(4096);
    f_deg<<<egrid, blk, 0, stream>>>(col, ew, Aw);
    f_dis<<<ngrid, blk, 0, stream>>>(Aw);
    f_scatter<<<egrid, blk, 0, stream>>>(row, col, ew, Aw, x, Bw);
    f_g<<<ngrid, blk, 0, stream>>>(Aw, x, Bw, W1, b1, W2);
    f_scatter<<<egrid, blk, 0, stream>>>(row, col, ew, Aw, Bw, Cw);
    f_out<<<ngrid, blk, 0, stream>>>(Aw, Bw, Cw, b2, Wl, bl);
  }
}

// Round 18
// 307.052 us; speedup vs baseline: 1.0374x; 1.0374x over previous
//
#include <hip/hip_runtime.h>

// GCN on 1M nodes / 16M edges, collapsed to scalar per-node features.
//
//   deg[c]  = sum_{c: col=c} ew[e] + 1 (self loop)
//   dis     = rsqrt(deg)
//   S1[c]   = dis[c] * (sum_e dis[row]*ew*x[row]) + dis[c]^2 * x[c]
//   g[c]    = sum_j relu(S1[c]*W1[j] + b1[j]) * W2[j]
//   S2[c]   = dis[c] * (sum_e dis[row]*ew*g[row]) + dis[c]^2 * g[c]
//   y[c]    = sigmoid((S2[c]+b2)*Wl + bl)
//
// R17 post-mortem: zero-atomic fill (slot-passing) did NOT speed fill and
// its +32MB slot stream cost ~10us net -> fill is stream+reorder bound
// (~100us across atomics/no-atomics, 34/68% occupancy, 2 chunk sizes).
// R18: revert to R16 (best measured 308.7us). Ledger: fill ~100 (stream),
// count ~28, 3x fixed-point acc ~150, scans ~18, node ~14. Remaining gap
// to pure-HBM (~130us) is the 64M LDS-atomic accumulate + reorder, both
// intrinsic to the scatter->gather design; alternatives measured worse
// (global atomics R2: 2363us, no reorder R3, row-sort R8: +310us).

constexpr int N_NODES = 1000000;
constexpr int N_EDGES = 16000000;

constexpr int BSHIFT = 12;
constexpr int BNODES = 1 << BSHIFT;                    // 4096 nodes/bucket
constexpr int NB = (N_NODES + BNODES - 1) / BNODES;    // 245 buckets
constexpr int FBLK_C = 512;                            // count threads
constexpr int EPT_C = 12;
constexpr int FBLK_F = 1024;                           // fill threads
constexpr int EPT_F = 6;
constexpr int CHUNK = FBLK_C * EPT_C;                  // 6144 (== FBLK_F*EPT_F)
constexpr int NBLK = (N_EDGES + CHUNK - 1) / CHUNK;    // 2605
constexpr int NHIST = NB * NBLK;                       // 638,225
constexpr int SCAN_TPB = 256;
constexpr int SCAN_EPB = 1024;
constexpr int NSCAN = (NHIST + SCAN_EPB - 1) / SCAN_EPB;  // 624
constexpr int NHIST_PAD = NSCAN * SCAN_EPB;            // 638,976

__device__ inline unsigned short f2bf(float f) {   // fp32 -> bf16 RNE
  unsigned u = __float_as_uint(f);
  return (unsigned short)((u + 0x7FFFu + ((u >> 16) & 1u)) >> 16);
}
__device__ inline float bf2f(unsigned short h) {
  return __uint_as_float((unsigned)h << 16);
}
// packed-pair bf16 unpack: lo = u<<16 (1 op), hi = u & 0xFFFF0000 (1 op)
__device__ inline float blo(unsigned u) { return __uint_as_float(u << 16); }
__device__ inline float bhi(unsigned u) { return __uint_as_float(u & 0xFFFF0000u); }

// ---------------- build: count / transpose / scan / transpose / fill --------

// histT layout [NBLK][256]: block writes its own contiguous row (coalesced).
__global__ __launch_bounds__(FBLK_C) void k_count(const int* __restrict__ col,
                                                  unsigned* __restrict__ histT) {
  __shared__ unsigned cnt[256];
  int t = threadIdx.x;
  if (t < 256) cnt[t] = 0;
  __syncthreads();
  int e0 = blockIdx.x * CHUNK;
  if (e0 + CHUNK <= N_EDGES) {          // fast path: all loads unguarded
    int c[EPT_C];
#pragma unroll
    for (int k = 0; k < EPT_C; ++k) c[k] = col[e0 + k * FBLK_C + t];
    __builtin_amdgcn_sched_barrier(0);  // keep the load batch issued together
#pragma unroll
    for (int k = 0; k < EPT_C; ++k) atomicAdd(&cnt[c[k] >> BSHIFT], 1u);
  } else {
#pragma unroll
    for (int k = 0; k < EPT_C; ++k) {
      int e = e0 + k * FBLK_C + t;
      if (e < N_EDGES) atomicAdd(&cnt[col[e] >> BSHIFT], 1u);
    }
  }
  __syncthreads();
  if (t < 256) histT[(size_t)blockIdx.x * 256 + t] = cnt[t];
}

// histT[NBLK][256] -> hist[b*NBLK + blk] (bucket-major flat, for linear scan)
__global__ __launch_bounds__(1024) void k_t1(const unsigned* __restrict__ in,
                                             unsigned* __restrict__ out) {
  __shared__ unsigned tile[32][33];
  int bx = blockIdx.x * 32;   // blk base
  int by = blockIdx.y * 32;   // b base
  int tx = threadIdx.x, ty = threadIdx.y;
  int rblk = bx + ty;
  if (rblk < NBLK) tile[ty][tx] = in[(size_t)rblk * 256 + by + tx];
  __syncthreads();
  int wb = by + ty, wblk = bx + tx;
  if (wb < NB && wblk < NBLK) out[(size_t)wb * NBLK + wblk] = tile[tx][ty];
}

// hist offsets (bucket-major) -> histT2[blk*256 + b] (fill reads coalesced)
__global__ __launch_bounds__(1024) void k_t2(const unsigned* __restrict__ in,
                                             unsigned* __restrict__ out) {
  __shared__ unsigned tile[32][33];
  int bx = blockIdx.x * 32;   // blk base
  int by = blockIdx.y * 32;   // b base
  int tx = threadIdx.x, ty = threadIdx.y;
  int rb = by + ty, rblk = bx + tx;
  if (rb < NB && rblk < NBLK) tile[ty][tx] = in[(size_t)rb * NBLK + rblk];
  __syncthreads();
  int wblk = bx + ty, wb = by + tx;
  if (wblk < NBLK && wb < NB) out[(size_t)wblk * 256 + wb] = tile[tx][ty];
}

__global__ __launch_bounds__(SCAN_TPB) void k_scanA(unsigned* __restrict__ h,
                                                    unsigned* __restrict__ bsum) {
  __shared__ unsigned sc[SCAN_TPB];
  int t = threadIdx.x;
  size_t base = (size_t)blockIdx.x * SCAN_EPB + (size_t)t * 4;
  uint4 v = *(const uint4*)(h + base);
  unsigned s = v.x + v.y + v.z + v.w;
  sc[t] = s;
  __syncthreads();
  for (int d = 1; d < SCAN_TPB; d <<= 1) {
    unsigned u = (t >= d) ? sc[t - d] : 0;
    __syncthreads();
    sc[t] += u;
    __syncthreads();
  }
  unsigned ex = sc[t] - s;
  uint4 o;
  o.x = ex; o.y = ex + v.x; o.z = ex + v.x + v.y; o.w = ex + v.x + v.y + v.z;
  *(uint4*)(h + base) = o;
  if (t == SCAN_TPB - 1) bsum[blockIdx.x] = sc[t];
}

__global__ __launch_bounds__(1024) void k_scanB(unsigned* __restrict__ bsum) {
  __shared__ unsigned sc[1024];
  int t = threadIdx.x;
  unsigned a0 = (2 * t < NSCAN) ? bsum[2 * t] : 0;
  unsigned a1 = (2 * t + 1 < NSCAN) ? bsum[2 * t + 1] : 0;
  unsigned s = a0 + a1;
  sc[t] = s;
  __syncthreads();
  for (int d = 1; d < 1024; d <<= 1) {
    unsigned u = (t >= d) ? sc[t - d] : 0;
    __syncthreads();
    sc[t] += u;
    __syncthreads();
  }
  unsigned ex = sc[t] - s;
  if (2 * t < NSCAN) bsum[2 * t] = ex;
  if (2 * t + 1 < NSCAN) bsum[2 * t + 1] = ex + a0;
}

__global__ __launch_bounds__(SCAN_TPB) void k_scanC(unsigned* __restrict__ h,
                                                    const unsigned* __restrict__ bsum) {
  unsigned add = bsum[blockIdx.x];
  size_t base = (size_t)blockIdx.x * SCAN_EPB + (size_t)threadIdx.x * 4;
  uint4 v = *(uint4*)(h + base);
  v.x += add; v.y += add; v.z += add; v.w += add;
  *(uint4*)(h + base) = v;
}

// Register-stash + LDS-reorder fill, SoA output: PK (u32) + W16 (bf16).
// pk = row<<12 | col&0xFFF; row < 2^20 fits.
// 1024 threads x 6 edges (CHUNK 6144 unchanged); ~47KB LDS -> 32 waves/CU.
__global__ __launch_bounds__(FBLK_F) void k_fill(const int* __restrict__ row,
                                                 const int* __restrict__ col,
                                                 const float* __restrict__ ew,
                                                 const unsigned* __restrict__ histT2,
                                                 unsigned* __restrict__ PK,
                                                 unsigned short* __restrict__ W16) {
  __shared__ unsigned lhist[256];
  __shared__ unsigned lb[256];
  __shared__ unsigned tail[256];
  __shared__ unsigned gbase[NB];
  __shared__ unsigned wsum[4];
  __shared__ unsigned spk[CHUNK];          // 24KB
  __shared__ unsigned short sw[CHUNK];     // 12KB
  __shared__ unsigned char sbkt[CHUNK];    // 6KB

  int t = threadIdx.x;
  int blk = blockIdx.x;
  if (t < 256) lhist[t] = 0;
  if (t < NB) gbase[t] = histT2[(size_t)blk * 256 + t];  // coalesced row read
  __syncthreads();                                        // B1

  int e0 = blk * CHUNK;
  unsigned pk[EPT_F];
  unsigned short wv[EPT_F];
  int bk[EPT_F];
  if (e0 + CHUNK <= N_EDGES) {          // fast path (2604 of 2605 blocks)
    int cv[EPT_F], rv[EPT_F];
    float wf[EPT_F];
#pragma unroll
    for (int k = 0; k < EPT_F; ++k) {
      int e = e0 + k * FBLK_F + t;
      cv[k] = col[e];
      rv[k] = row[e];
      wf[k] = ew[e];
    }
    __builtin_amdgcn_sched_barrier(0);  // 18 loads in flight before any use
#pragma unroll
    for (int k = 0; k < EPT_F; ++k) {
      pk[k] = ((unsigned)rv[k] << BSHIFT) | (unsigned)(cv[k] & (BNODES - 1));
      wv[k] = f2bf(wf[k]);
      bk[k] = cv[k] >> BSHIFT;
    }
#pragma unroll
    for (int k = 0; k < EPT_F; ++k) atomicAdd(&lhist[bk[k]], 1u);
  } else {
#pragma unroll
    for (int k = 0; k < EPT_F; ++k) {
      int e = e0 + k * FBLK_F + t;
      bk[k] = -1;
      if (e < N_EDGES) {
        int c = col[e];
        pk[k] = ((unsigned)row[e] << BSHIFT) | (unsigned)(c & (BNODES - 1));
        wv[k] = f2bf(ew[e]);
        bk[k] = c >> BSHIFT;
        atomicAdd(&lhist[bk[k]], 1u);
      }
    }
  }
  __syncthreads();                                        // B2

  // exclusive prefix over 256 bucket counts (threads 0-255 = 4 waves)
  unsigned own = 0, v = 0;
  if (t < 256) {
    own = lhist[t];
    v = own;
#pragma unroll
    for (int d = 1; d < 64; d <<= 1) {
      unsigned u = __shfl_up(v, d, 64);
      if ((t & 63) >= d) v += u;
    }
    if ((t & 63) == 63) wsum[t >> 6] = v;
  }
  __syncthreads();                                        // B3
  unsigned total = wsum[0] + wsum[1] + wsum[2] + wsum[3];
  if (t < 256) {
    unsigned wbase = 0;
#pragma unroll
    for (int w = 0; w < 4; ++w)
      if (w < (t >> 6)) wbase += wsum[w];
    unsigned ex = wbase + v - own;
    lb[t] = ex;
    tail[t] = ex;
  }
  __syncthreads();                                        // B4

  if (e0 + CHUNK <= N_EDGES) {
#pragma unroll
    for (int k = 0; k < EPT_F; ++k) {
      unsigned s = atomicAdd(&tail[bk[k]], 1u);
      spk[s] = pk[k];
      sw[s] = wv[k];
      sbkt[s] = (unsigned char)bk[k];
    }
  } else {
#pragma unroll
    for (int k = 0; k < EPT_F; ++k) {
      if (bk[k] >= 0) {
        unsigned s = atomicAdd(&tail[bk[k]], 1u);
        spk[s] = pk[k];
        sw[s] = wv[k];
        sbkt[s] = (unsigned char)bk[k];
      }
    }
  }
  __syncthreads();                                        // B5

  // staged order is bucket-sorted: consecutive s -> consecutive global dest.
  unsigned s = t;
  for (; s + 3u * FBLK_F < total; s += 4u * FBLK_F) {
#pragma unroll
    for (int u = 0; u < 4; ++u) {
      unsigned si = s + u * FBLK_F;
      unsigned b = sbkt[si];
      unsigned idx = gbase[b] + (si - lb[b]);
      PK[idx] = spk[si];
      W16[idx] = sw[si];
    }
  }
  for (; s < total; s += FBLK_F) {
    unsigned b = sbkt[s];
    unsigned idx = gbase[b] + (s - lb[b]);
    PK[idx] = spk[s];
    W16[idx] = sw[s];
  }
}

// ---------------- accumulate: one (bucket,part) per block ----------------
// mode 0: val = ew. mode 1: val = ew * bf16 p16[row].
// FIXED-POINT LDS accumulator (ds_add_u32 ~5x faster than ds_add_f32).
constexpr int ABLK = 512;

__global__ __launch_bounds__(ABLK) void k_acc(const unsigned* __restrict__ PK,
                                              const unsigned short* __restrict__ W16,
                                              const unsigned* __restrict__ hist,
                                              const unsigned short* __restrict__ p16,
                                              float* __restrict__ out,
                                              int mode, int split,
                                              float FS, float INV) {
  __shared__ int acc[BNODES];
  {
    int4* a4 = (int4*)acc;
#pragma unroll
    for (int i = threadIdx.x; i < BNODES / 4; i += ABLK)
      a4[i] = make_int4(0, 0, 0, 0);
  }
  __syncthreads();
  int b = blockIdx.x / split;
  int part = blockIdx.x - b * split;
  unsigned bs = hist[(size_t)b * NBLK];
  unsigned be = (b + 1 < NB) ? hist[(size_t)(b + 1) * NBLK] : (unsigned)N_EDGES;
  unsigned len = be - bs;
  unsigned s = bs + (unsigned)(((unsigned long long)len * part) / split);
  unsigned e = bs + (unsigned)(((unsigned long long)len * (part + 1)) / split);
  unsigned t = threadIdx.x;

  unsigned s_al = (s + 7u) & ~7u;        // align to 8 records
  if (s_al > e) s_al = e;
  if (t == 0) {                          // scalar head (<8 records)
    for (unsigned i = s; i < s_al; ++i) {
      unsigned pk = PK[i];
      float v = bf2f(W16[i]);
      if (mode) v *= bf2f(p16[pk >> BSHIFT]);
      atomicAdd(&acc[pk & (BNODES - 1)], __float2int_rn(v * FS));
    }
  }
  s = s_al;
  unsigned n = (e > s) ? (e - s) : 0u;
  unsigned ng = n >> 3;                  // groups of 8 records
  const uint4* pk4 = (const uint4*)(PK + s);    // group g: pk4[2g], pk4[2g+1]
  const uint4* w4  = (const uint4*)(W16 + s);   // group g: w4[g] (8 bf16)

  unsigned ip = t;
  for (; ip + ABLK < ng; ip += 2u * ABLK) {     // 2 groups = 16 records
    unsigned g1 = ip + ABLK;
    uint4 pA0 = pk4[2u * ip], pA1 = pk4[2u * ip + 1u];
    uint4 pB0 = pk4[2u * g1], pB1 = pk4[2u * g1 + 1u];
    uint4 wA = w4[ip], wB = w4[g1];
    __builtin_amdgcn_sched_barrier(0);   // 6 loads issued before any use
    if (mode) {
      unsigned short gA0 = p16[pA0.x >> BSHIFT], gA1 = p16[pA0.y >> BSHIFT];
      unsigned short gA2 = p16[pA0.z >> BSHIFT], gA3 = p16[pA0.w >> BSHIFT];
      unsigned short gA4 = p16[pA1.x >> BSHIFT], gA5 = p16[pA1.y >> BSHIFT];
      unsigned short gA6 = p16[pA1.z >> BSHIFT], gA7 = p16[pA1.w >> BSHIFT];
      unsigned short gB0 = p16[pB0.x >> BSHIFT], gB1 = p16[pB0.y >> BSHIFT];
      unsigned short gB2 = p16[pB0.z >> BSHIFT], gB3 = p16[pB0.w >> BSHIFT];
      unsigned short gB4 = p16[pB1.x >> BSHIFT], gB5 = p16[pB1.y >> BSHIFT];
      unsigned short gB6 = p16[pB1.z >> BSHIFT], gB7 = p16[pB1.w >> BSHIFT];
      __builtin_amdgcn_sched_barrier(0); // 16 gathers in flight before use
      atomicAdd(&acc[pA0.x & (BNODES - 1)], __float2int_rn(blo(wA.x) * bf2f(gA0) * FS));
      atomicAdd(&acc[pA0.y & (BNODES - 1)], __float2int_rn(bhi(wA.x) * bf2f(gA1) * FS));
      atomicAdd(&acc[pA0.z & (BNODES - 1)], __float2int_rn(blo(wA.y) * bf2f(gA2) * FS));
      atomicAdd(&acc[pA0.w & (BNODES - 1)], __float2int_rn(bhi(wA.y) * bf2f(gA3) * FS));
      atomicAdd(&acc[pA1.x & (BNODES - 1)], __float2int_rn(blo(wA.z) * bf2f(gA4) * FS));
      atomicAdd(&acc[pA1.y & (BNODES - 1)], __float2int_rn(bhi(wA.z) * bf2f(gA5) * FS));
      atomicAdd(&acc[pA1.z & (BNODES - 1)], __float2int_rn(blo(wA.w) * bf2f(gA6) * FS));
      atomicAdd(&acc[pA1.w & (BNODES - 1)], __float2int_rn(bhi(wA.w) * bf2f(gA7) * FS));
      atomicAdd(&acc[pB0.x & (BNODES - 1)], __float2int_rn(blo(wB.x) * bf2f(gB0) * FS));
      atomicAdd(&acc[pB0.y & (BNODES - 1)], __float2int_rn(bhi(wB.x) * bf2f(gB1) * FS));
      atomicAdd(&acc[pB0.z & (BNODES - 1)], __float2int_rn(blo(wB.y) * bf2f(gB2) * FS));
      atomicAdd(&acc[pB0.w & (BNODES - 1)], __float2int_rn(bhi(wB.y) * bf2f(gB3) * FS));
      atomicAdd(&acc[pB1.x & (BNODES - 1)], __float2int_rn(blo(wB.z) * bf2f(gB4) * FS));
      atomicAdd(&acc[pB1.y & (BNODES - 1)], __float2int_rn(bhi(wB.z) * bf2f(gB5) * FS));
      atomicAdd(&acc[pB1.z & (BNODES - 1)], __float2int_rn(blo(wB.w) * bf2f(gB6) * FS));
      atomicAdd(&acc[pB1.w & (BNODES - 1)], __float2int_rn(bhi(wB.w) * bf2f(gB7) * FS));
    } else {
      atomicAdd(&acc[pA0.x & (BNODES - 1)], __float2int_rn(blo(wA.x) * FS));
      atomicAdd(&acc[pA0.y & (BNODES - 1)], __float2int_rn(bhi(wA.x) * FS));
      atomicAdd(&acc[pA0.z & (BNODES - 1)], __float2int_rn(blo(wA.y) * FS));
      atomicAdd(&acc[pA0.w & (BNODES - 1)], __float2int_rn(bhi(wA.y) * FS));
      atomicAdd(&acc[pA1.x & (BNODES - 1)], __float2int_rn(blo(wA.z) * FS));
      atomicAdd(&acc[pA1.y & (BNODES - 1)], __float2int_rn(bhi(wA.z) * FS));
      atomicAdd(&acc[pA1.z & (BNODES - 1)], __float2int_rn(blo(wA.w) * FS));
      atomicAdd(&acc[pA1.w & (BNODES - 1)], __float2int_rn(bhi(wA.w) * FS));
      atomicAdd(&acc[pB0.x & (BNODES - 1)], __float2int_rn(blo(wB.x) * FS));
      atomicAdd(&acc[pB0.y & (BNODES - 1)], __float2int_rn(bhi(wB.x) * FS));
      atomicAdd(&acc[pB0.z & (BNODES - 1)], __float2int_rn(blo(wB.y) * FS));
      atomicAdd(&acc[pB0.w & (BNODES - 1)], __float2int_rn(bhi(wB.y) * FS));
      atomicAdd(&acc[pB1.x & (BNODES - 1)], __float2int_rn(blo(wB.z) * FS));
      atomicAdd(&acc[pB1.y & (BNODES - 1)], __float2int_rn(bhi(wB.z) * FS));
      atomicAdd(&acc[pB1.z & (BNODES - 1)], __float2int_rn(blo(wB.w) * FS));
      atomicAdd(&acc[pB1.w & (BNODES - 1)], __float2int_rn(bhi(wB.w) * FS));
    }
  }
  for (; ip < ng; ip += 2u * ABLK) {     // leftover single group (8 records)
    uint4 p0 = pk4[2u * ip], p1 = pk4[2u * ip + 1u];
    uint4 w = w4[ip];
    float v0 = blo(w.x), v1 = bhi(w.x), v2 = blo(w.y), v3 = bhi(w.y);
    float v4 = blo(w.z), v5 = bhi(w.z), v6 = blo(w.w), v7 = bhi(w.w);
    if (mode) {
      v0 *= bf2f(p16[p0.x >> BSHIFT]); v1 *= bf2f(p16[p0.y >> BSHIFT]);
      v2 *= bf2f(p16[p0.z >> BSHIFT]); v3 *= bf2f(p16[p0.w >> BSHIFT]);
      v4 *= bf2f(p16[p1.x >> BSHIFT]); v5 *= bf2f(p16[p1.y >> BSHIFT]);
      v6 *= bf2f(p16[p1.z >> BSHIFT]); v7 *= bf2f(p16[p1.w >> BSHIFT]);
    }
    atomicAdd(&acc[p0.x & (BNODES - 1)], __float2int_rn(v0 * FS));
    atomicAdd(&acc[p0.y & (BNODES - 1)], __float2int_rn(v1 * FS));
    atomicAdd(&acc[p0.z & (BNODES - 1)], __float2int_rn(v2 * FS));
    atomicAdd(&acc[p0.w & (BNODES - 1)], __float2int_rn(v3 * FS));
    atomicAdd(&acc[p1.x & (BNODES - 1)], __float2int_rn(v4 * FS));
    atomicAdd(&acc[p1.y & (BNODES - 1)], __float2int_rn(v5 * FS));
    atomicAdd(&acc[p1.z & (BNODES - 1)], __float2int_rn(v6 * FS));
    atomicAdd(&acc[p1.w & (BNODES - 1)], __float2int_rn(v7 * FS));
  }
  unsigned rem = n & 7u;                 // scalar tail, threads 0..rem-1
  if (t < rem) {
    unsigned i = s + (n - rem) + t;
    unsigned pk = PK[i];
    float v = bf2f(W16[i]);
    if (mode) v *= bf2f(p16[pk >> BSHIFT]);
    atomicAdd(&acc[pk & (BNODES - 1)], __float2int_rn(v * FS));
  }
  __syncthreads();

  float* o = out + (size_t)part * N_NODES;
  int base = b * BNODES;
  if (base + BNODES <= N_NODES) {        // full bucket: float4 writeout
    float4* o4 = (float4*)(o + base);
    const int4* a4 = (const int4*)acc;
#pragma unroll
    for (int j = threadIdx.x; j < BNODES / 4; j += ABLK) {
      int4 q = a4[j];
      o4[j] = make_float4((float)q.x * INV, (float)q.y * INV,
                          (float)q.z * INV, (float)q.w * INV);
    }
  } else {
    for (int j = threadIdx.x; base + j < N_NODES; j += ABLK)
      o[base + j] = (float)acc[j] * INV;
  }
}

// ---------------- node-wise kernels ----------------

__global__ void k_dis_p(const float* __restrict__ x, const float* __restrict__ D,
                        float* __restrict__ A, unsigned short* __restrict__ P16,
                        int split) {
  int i = blockIdx.x * blockDim.x + threadIdx.x;
  if (i >= N_NODES) return;
  float deg = 1.0f;                       // self loop
  for (int j = 0; j < split; ++j) deg += D[(size_t)j * N_NODES + i];
  float d = rsqrtf(deg);
  A[i] = d;
  P16[i] = f2bf(d * x[i]);
}

__global__ void k_g2(const float* __restrict__ A, const float* __restrict__ x,
                     const float* __restrict__ D, unsigned short* __restrict__ P16,
                     const float* __restrict__ W1, const float* __restrict__ b1,
                     const float* __restrict__ W2, int split) {
  int i = blockIdx.x * blockDim.x + threadIdx.x;
  if (i >= N_NODES) return;
  float d = A[i];
  float sraw = 0.f;
  for (int j = 0; j < split; ++j) sraw += D[(size_t)j * N_NODES + i];
  float s1 = d * sraw + d * d * x[i];
  float g = 0.f;
#pragma unroll
  for (int j = 0; j < 4; ++j) {
    float h = fmaf(s1, W1[j], b1[j]);
    g = fmaf(fmaxf(h, 0.f), W2[j], g);
  }
  P16[i] = f2bf(d * g);
}

__global__ void k_out2(const float* __restrict__ A,
                       const unsigned short* __restrict__ P16,
                       const float* __restrict__ D, const float* __restrict__ b2,
                       const float* __restrict__ Wl, const float* __restrict__ bl,
                       float* __restrict__ y, int split) {
  int i = blockIdx.x * blockDim.x + threadIdx.x;
  if (i >= N_NODES) return;
  float d = A[i];
  float g = bf2f(P16[i]) / d;             // d in (0,1], safe
  float sraw = 0.f;
  for (int j = 0; j < split; ++j) sraw += D[(size_t)j * N_NODES + i];
  float agg2 = d * sraw + d * d * g;
  float v = fmaf(agg2 + b2[0], Wl[0], bl[0]);
  y[i] = 1.0f / (1.0f + expf(-v));
}

// ---------------- fallback (round-2 global-atomic path) ----------------

__global__ void f_deg(const int* __restrict__ col, const float* __restrict__ ew,
                      float* __restrict__ deg) {
  int i = blockIdx.x * blockDim.x + threadIdx.x;
  int stride = gridDim.x * blockDim.x;
  for (int e = i; e < N_EDGES; e += stride) atomicAdd(&deg[col[e]], ew[e]);
}
__global__ void f_dis(float* __restrict__ a) {
  int i = blockIdx.x * blockDim.x + threadIdx.x;
  if (i < N_NODES) a[i] = rsqrtf(a[i] + 1.0f);
}
__global__ void f_scatter(const int* __restrict__ row, const int* __restrict__ col,
                          const float* __restrict__ ew, const float* __restrict__ dis,
                          const float* __restrict__ src, float* __restrict__ acc) {
  int i = blockIdx.x * blockDim.x + threadIdx.x;
  int stride = gridDim.x * blockDim.x;
  for (int e = i; e < N_EDGES; e += stride) {
    int r = row[e]; int c = col[e];
    atomicAdd(&acc[c], dis[r] * ew[e] * src[r]);
  }
}
__global__ void f_g(const float* __restrict__ dis, const float* __restrict__ x,
                    float* __restrict__ s1g, const float* __restrict__ W1,
                    const float* __restrict__ b1, const float* __restrict__ W2) {
  int i = blockIdx.x * blockDim.x + threadIdx.x;
  if (i >= N_NODES) return;
  float d = dis[i];
  float s1 = d * s1g[i] + d * d * x[i];
  float g = 0.f;
#pragma unroll
  for (int j = 0; j < 4; ++j) {
    float h = fmaf(s1, W1[j], b1[j]);
    g = fmaf(fmaxf(h, 0.f), W2[j], g);
  }
  s1g[i] = g;
}
__global__ void f_out(const float* __restrict__ dis, const float* __restrict__ g,
                      float* __restrict__ s2out, const float* __restrict__ b2,
                      const float* __restrict__ Wl, const float* __restrict__ bl) {
  int i = blockIdx.x * blockDim.x + threadIdx.x;
  if (i >= N_NODES) return;
  float d = dis[i];
  float agg2 = d * s2out[i] + d * d * g[i];
  float v = fmaf(agg2 + b2[0], Wl[0], bl[0]);
  s2out[i] = 1.0f / (1.0f + expf(-v));
}

// ---------------- launch ----------------

extern "C" void kernel_launch(void* const* d_in, const int* in_sizes, int n_in,
                              void* d_out, int out_size, void* d_ws, size_t ws_size,
                              hipStream_t stream) {
  const float* x  = (const float*)d_in[0];
  const int* ei   = (const int*)d_in[1];   // int32 (harness narrows int64)
  const float* ew = (const float*)d_in[2];
  const float* W1 = (const float*)d_in[3];
  const float* b1 = (const float*)d_in[4];
  const float* W2 = (const float*)d_in[5];
  const float* b2 = (const float*)d_in[6];
  const float* Wl = (const float*)d_in[7];
  const float* bl = (const float*)d_in[8];

  const int* row = ei;
  const int* col = ei + N_EDGES;

  auto pad = [](size_t v) { return (v + 255) & ~(size_t)255; };
  const size_t PK_B    = pad((size_t)N_EDGES * 4);         // 64,000,000
  const size_t W16_B   = pad((size_t)N_EDGES * 2);         // 32,000,000
  const size_t HIST_B  = pad((size_t)NHIST_PAD * 4);       // 2,555,904
  const size_t HISTT_B = pad((size_t)NBLK * 256 * 4);      // 2,667,520
  const size_t BSUM_B  = 8192;
  const size_t NODE_B  = pad((size_t)N_NODES * 4);
  const size_t P16_B   = pad((size_t)N_NODES * 2);
  const size_t BASE    = PK_B + W16_B + HIST_B + HISTT_B + BSUM_B + NODE_B + P16_B;

  dim3 blk(256);
  dim3 ngrid((N_NODES + 255) / 256);
  dim3 tgrid((NBLK + 31) / 32, 8);
  dim3 tblk(32, 32);

  // fixed-point scales: deg <= 64 -> 2^22 (max 2^28); s1/s2 worst |sum| ~2e5
  // -> 2^12 (range +-2^19 after sum; resolution 2.4e-4 << absmax margin)
  const float FS0 = 4194304.f, INV0 = 1.f / 4194304.f;
  const float FS1 = 4096.f,    INV1 = 1.f / 4096.f;

  int split = 0;
  for (int s : {4, 2, 1})
    if (ws_size >= BASE + (size_t)s * NODE_B) { split = s; break; }

  if (split) {
    char* w = (char*)d_ws;
    unsigned* PK        = (unsigned*)w;
    unsigned short* W16 = (unsigned short*)(w + PK_B);
    unsigned* hist      = (unsigned*)(w + PK_B + W16_B);
    unsigned* histT     = (unsigned*)(w + PK_B + W16_B + HIST_B);  // also histT2
    unsigned* bsum      = (unsigned*)(w + PK_B + W16_B + HIST_B + HISTT_B);
    float* A            = (float*)(w + PK_B + W16_B + HIST_B + HISTT_B + BSUM_B);
    unsigned short* P16 = (unsigned short*)((char*)A + NODE_B);
    float* D            = (float*)((char*)P16 + P16_B);    // split partials

    // zero the scan pad tail (rest of hist fully written by k_t1)
    hipMemsetAsync(hist + NHIST, 0, (size_t)(NHIST_PAD - NHIST) * 4, stream);

    k_count<<<NBLK, FBLK_C, 0, stream>>>(col, histT);
    k_t1   <<<tgrid, tblk, 0, stream>>>(histT, hist);
    k_scanA<<<NSCAN, SCAN_TPB, 0, stream>>>(hist, bsum);
    k_scanB<<<1, 1024, 0, stream>>>(bsum);
    k_scanC<<<NSCAN, SCAN_TPB, 0, stream>>>(hist, bsum);
    k_t2   <<<tgrid, tblk, 0, stream>>>(hist, histT);      // offsets, transposed
    k_fill <<<NBLK, FBLK_F, 0, stream>>>(row, col, ew, histT, PK, W16);

    k_acc  <<<NB * split, ABLK, 0, stream>>>(PK, W16, hist, nullptr, D, 0, split, FS0, INV0);
    k_dis_p<<<ngrid, blk, 0, stream>>>(x, D, A, P16, split);
    k_acc  <<<NB * split, ABLK, 0, stream>>>(PK, W16, hist, P16, D, 1, split, FS1, INV1);
    k_g2   <<<ngrid, blk, 0, stream>>>(A, x, D, P16, W1, b1, W2, split);
    k_acc  <<<NB * split, ABLK, 0, stream>>>(PK, W16, hist, P16, D, 1, split, FS1, INV1);
    k_out2 <<<ngrid, blk, 0, stream>>>(A, P16, D, b2, Wl, bl, (float*)d_out, split);
  } else {
    float* Aw = (float*)d_ws;
    float* Bw = Aw + N_NODES;
    float* Cw = (float*)d_out;
    hipMemsetAsync(d_ws, 0, 2ull * N_NODES * 4, stream);
    hipMemsetAsync(d_out, 0, (size_t)N_NODES * 4, stream);
    dim3 egrid(4096);
    f_deg<<<egrid, blk, 0, stream>>>(col, ew, Aw);
    f_dis<<<ngrid, blk, 0, stream>>>(Aw);
    f_scatter<<<egrid, blk, 0, stream>>>(row, col, ew, Aw, x, Bw);
    f_g<<<ngrid, blk, 0, stream>>>(Aw, x, Bw, W1, b1, W2);
    f_scatter<<<egrid, blk, 0, stream>>>(row, col, ew, Aw, Bw, Cw);
    f_out<<<ngrid, blk, 0, stream>>>(Aw, Bw, Cw, b2, Wl, bl);
  }
}